// Round 5
// baseline (928.285 us; speedup 1.0000x reference)
//
#include <hip/hip_runtime.h>
#include <math.h>

// InstantNGP-style hash-grid encoder, 16 levels, FEAT=2, B=2M points.
//   res: ceil(16*exp(i*ln(128)/15) - 1) + 1
//   dense levels 0..4 (res^3 <= 2^19), hashed levels 5..15 (size = 2^19 each)
//
// Measured model (r4): divergent gathers cost ~2 cyc/lane-request/CU (TA-bound).
// So: minimize lane-requests.
//   - fine levels: x-corner pairing. hash h = pgx ^ (pgy*P2) ^ (pgz*P3); for
//     even gx, h(cx=1) = h(cx=0)^1 -> adjacent 16B-aligned table pair -> one
//     16B load serves both corners. Odd-gx lanes issue one extra 8B load.
//   - dense levels: x-pairs are always adjacent (stride 1) -> 16B loads.
//   - ws staged as packed bf16x2 (RNE): halves ws streaming; adds <=1.2e-7.
#define NLEVELS 16
#define BEGIN_FAST 5
#define P2 2654435761u
#define P3 805459861u
#define FAST_MASK 524287u  // size = 2^19 for all hashed levels

constexpr unsigned kRes[NLEVELS] = {16u, 23u, 31u, 43u, 59u, 81u, 112u, 154u, 213u, 295u, 407u, 562u, 777u, 1073u, 1483u, 2048u};
constexpr unsigned kSize[NLEVELS] = {
    4096u, 12168u, 29792u, 79512u, 205384u,
    524288u, 524288u, 524288u, 524288u, 524288u, 524288u,
    524288u, 524288u, 524288u, 524288u, 524288u};
constexpr unsigned kOffset[NLEVELS] = {
    0u,       4096u,    16264u,   46056u,   125568u,  330952u,
    855240u,  1379528u, 1903816u, 2428104u, 2952392u, 3476680u,
    4000968u, 4525256u, 5049544u, 5573832u};

struct Scales {
    float s[NLEVELS];
};

typedef float fvec2 __attribute__((ext_vector_type(2)));
typedef float fvec4 __attribute__((ext_vector_type(4)));
typedef float fvec4a8 __attribute__((ext_vector_type(4), aligned(8)));

// pack two f32 -> bf16x2 (round-to-nearest-even), lo = a, hi = b
__device__ __forceinline__ unsigned bfpack(float a, float b) {
    unsigned ua = __float_as_uint(a);
    unsigned ub = __float_as_uint(b);
    ua = (ua + 0x7FFFu + ((ua >> 16) & 1u)) >> 16;
    ub = (ub + 0x7FFFu + ((ub >> 16) & 1u)) & 0xFFFF0000u;
    return ua | ub;
}

// ---------------- fine (hashed) level: table slice pre-offset, 4MB, L2-fit ---
__global__ __launch_bounds__(256) void fine_level_kernel(
    const float* __restrict__ positions,  // [B,3]
    const float2* __restrict__ tab,       // table + level offset (524288 rows)
    unsigned* __restrict__ wsl,           // ws slice [B], bf16x2 packed
    int B, float s)
{
    int p = blockIdx.x * 256 + threadIdx.x;
    if (p >= B) return;

    const float x = __builtin_nontemporal_load(positions + 3 * p + 0);
    const float y = __builtin_nontemporal_load(positions + 3 * p + 1);
    const float z = __builtin_nontemporal_load(positions + 3 * p + 2);

    const float px = x * s + 0.5f;
    const float py = y * s + 0.5f;
    const float pz = z * s + 0.5f;
    const float flx = floorf(px), fly = floorf(py), flz = floorf(pz);
    const float rx = px - flx, ry = py - fly, rz = pz - flz;
    const unsigned gx = (unsigned)flx;
    const unsigned gy = (unsigned)fly;
    const unsigned gz = (unsigned)flz;
    const float wx0 = 1.0f - rx, wy0 = 1.0f - ry, wz0 = 1.0f - rz;

    const unsigned hy0 = gy * P2, hy1 = hy0 + P2;
    const unsigned hz0 = gz * P3, hz1 = hz0 + P3;
    const bool odd = (gx & 1u) != 0u;
    const unsigned gx1 = gx + 1u;

    float ax = 0.0f, ay = 0.0f;
#pragma unroll
    for (int cc = 0; cc < 4; ++cc) {              // (cy, cz)
        const unsigned cy = (unsigned)(cc & 1);
        const unsigned cz = (unsigned)(cc >> 1);
        const float wyz = (cy ? ry : wy0) * (cz ? rz : wz0);
        const unsigned A = (cy ? hy1 : hy0) ^ (cz ? hz1 : hz0);
        const unsigned i0 = (gx ^ A) & FAST_MASK;
        const unsigned base = i0 & ~1u;
        // 16B-aligned pair {base, base|1}; contains corner cx=0 always, and
        // also corner cx=1 when gx is even (h1 = h0 ^ 1).
        const fvec4 tt = *reinterpret_cast<const fvec4*>(tab + base);
        const bool lo = (i0 & 1u) == 0u;
        const float e0x = lo ? tt.x : tt.z;
        const float e0y = lo ? tt.y : tt.w;
        float e1x = lo ? tt.z : tt.x;
        float e1y = lo ? tt.w : tt.y;
        if (odd) {                                // divergent: ~half the lanes
            const unsigned i1 = (gx1 ^ A) & FAST_MASK;
            const float2 t1 = tab[i1];
            e1x = t1.x;
            e1y = t1.y;
        }
        ax += wyz * (wx0 * e0x + rx * e1x);
        ay += wyz * (wx0 * e0y + rx * e1y);
    }
    __builtin_nontemporal_store(bfpack(ax, ay), wsl + p);
}

// ---------------- dense levels 0..4 -> ws slices 0..4 ------------------------
__global__ __launch_bounds__(256) void dense_kernel(
    const float* __restrict__ positions,  // [B,3]
    const float2* __restrict__ table,     // full table
    unsigned* __restrict__ ws,            // slices [16][B]; writes 0..4
    int B, Scales sc)
{
    int p = blockIdx.x * 256 + threadIdx.x;
    if (p >= B) return;

    const float x = __builtin_nontemporal_load(positions + 3 * p + 0);
    const float y = __builtin_nontemporal_load(positions + 3 * p + 1);
    const float z = __builtin_nontemporal_load(positions + 3 * p + 2);

#pragma unroll
    for (int l = 0; l < BEGIN_FAST; ++l) {
        const float s = sc.s[l];
        const float px = x * s + 0.5f;
        const float py = y * s + 0.5f;
        const float pz = z * s + 0.5f;
        const float flx = floorf(px), fly = floorf(py), flz = floorf(pz);
        const float rx = px - flx, ry = py - fly, rz = pz - flz;
        const unsigned gx = (unsigned)flx;
        const unsigned gy = (unsigned)fly;
        const unsigned gz = (unsigned)flz;
        const float wx0 = 1.0f - rx, wy0 = 1.0f - ry, wz0 = 1.0f - rz;

        const float2* tab = table + kOffset[l];
        const unsigned res = kRes[l];

        float ax = 0.0f, ay = 0.0f;
#pragma unroll
        for (int cc = 0; cc < 4; ++cc) {          // (cy, cz); x-pair fused
            const unsigned cy = (unsigned)(cc & 1);
            const unsigned cz = (unsigned)(cc >> 1);
            const float wyz = (cy ? ry : wy0) * (cz ? rz : wz0);
            const unsigned h0 = gx + (gy + cy) * res + (gz + cz) * (res * res);
            const unsigned idx0 = h0 % kSize[l];
            const fvec4 tt = *reinterpret_cast<const fvec4a8*>(tab + idx0);
            float t1x = tt.z, t1y = tt.w;
            if (idx0 == kSize[l] - 1) {           // (h0+1) % size wrapped to 0
                const float2 tf = tab[0];
                t1x = tf.x; t1y = tf.y;
            }
            ax += wyz * (wx0 * tt.x + rx * t1x);
            ay += wyz * (wx0 * tt.y + rx * t1y);
        }
        __builtin_nontemporal_store(bfpack(ax, ay), ws + (size_t)l * (size_t)B + p);
    }
}

// ---------------- merge: pure streaming, no gathers --------------------------
__global__ __launch_bounds__(256) void merge_kernel(
    const unsigned* __restrict__ ws,  // [16][B] bf16x2 packed
    float* __restrict__ out,          // [B,32]
    int B)
{
    int p = blockIdx.x * 256 + threadIdx.x;
    if (p >= B) return;

    float o[2 * NLEVELS];
#pragma unroll
    for (int l = 0; l < NLEVELS; ++l) {
        const unsigned v = __builtin_nontemporal_load(ws + (size_t)l * (size_t)B + p);
        o[2 * l + 0] = __uint_as_float(v << 16);
        o[2 * l + 1] = __uint_as_float(v & 0xFFFF0000u);
    }
    float* op = out + (size_t)p * (2 * NLEVELS);
#pragma unroll
    for (int i = 0; i < 8; ++i) {
        fvec4 v = {o[4 * i + 0], o[4 * i + 1], o[4 * i + 2], o[4 * i + 3]};
        *(reinterpret_cast<fvec4*>(op) + i) = v;
    }
}

// ---------------- fallback: monolithic (if ws too small) ---------------------
__global__ __launch_bounds__(256) void hash_encode_kernel(
    const float* __restrict__ positions,
    const float2* __restrict__ table,
    float* __restrict__ out,
    int B, Scales sc)
{
    int p = blockIdx.x * 256 + threadIdx.x;
    if (p >= B) return;

    const float x = positions[3 * p + 0];
    const float y = positions[3 * p + 1];
    const float z = positions[3 * p + 2];

    float o[2 * NLEVELS];

#pragma unroll
    for (int l = 0; l < NLEVELS; ++l) {
        const float s = sc.s[l];
        const float px = x * s + 0.5f;
        const float py = y * s + 0.5f;
        const float pz = z * s + 0.5f;
        const float flx = floorf(px), fly = floorf(py), flz = floorf(pz);
        const float rx = px - flx, ry = py - fly, rz = pz - flz;
        const unsigned gx = (unsigned)flx;
        const unsigned gy = (unsigned)fly;
        const unsigned gz = (unsigned)flz;
        const float wx0 = 1.0f - rx, wy0 = 1.0f - ry, wz0 = 1.0f - rz;

        float ax = 0.0f, ay = 0.0f;
#pragma unroll
        for (int c = 0; c < 8; ++c) {
            const unsigned cx = (unsigned)(c & 1);
            const unsigned cy = (unsigned)((c >> 1) & 1);
            const unsigned cz = (unsigned)((c >> 2) & 1);
            const unsigned pgx = gx + cx;
            const unsigned pgy = gy + cy;
            const unsigned pgz = gz + cz;
            const float w = (cx ? rx : wx0) * (cy ? ry : wy0) * (cz ? rz : wz0);
            unsigned h;
            if (l < BEGIN_FAST) {
                h = pgx + pgy * kRes[l] + pgz * (kRes[l] * kRes[l]);
            } else {
                h = pgx ^ (pgy * P2) ^ (pgz * P3);
            }
            const unsigned idx = (h % kSize[l]) + kOffset[l];
            const float2 t = table[idx];
            ax += w * t.x;
            ay += w * t.y;
        }
        o[2 * l + 0] = ax;
        o[2 * l + 1] = ay;
    }

    float* op = out + (size_t)p * (2 * NLEVELS);
#pragma unroll
    for (int i = 0; i < 8; ++i) {
        fvec4 v = {o[4 * i + 0], o[4 * i + 1], o[4 * i + 2], o[4 * i + 3]};
        *(reinterpret_cast<fvec4*>(op) + i) = v;
    }
}

extern "C" void kernel_launch(void* const* d_in, const int* in_sizes, int n_in,
                              void* d_out, int out_size, void* d_ws, size_t ws_size,
                              hipStream_t stream) {
    const float* positions = (const float*)d_in[0];
    const float2* table = (const float2*)d_in[1];
    float* out = (float*)d_out;

    const int B = in_sizes[0] / 3;

    Scales sc;
    const double log_b = log(2048.0 / 16.0) / (NLEVELS - 1);
    for (int l = 0; l < NLEVELS; ++l) {
        sc.s[l] = (float)(16.0 * exp((double)l * log_b) - 1.0);
    }

    const int blocks = (B + 255) / 256;
    const size_t ws_need = (size_t)NLEVELS * (size_t)B * sizeof(unsigned);

    if (ws_size >= ws_need) {
        unsigned* ws = (unsigned*)d_ws;
        for (int l = BEGIN_FAST; l < NLEVELS; ++l) {
            fine_level_kernel<<<blocks, 256, 0, stream>>>(
                positions, table + kOffset[l],
                ws + (size_t)l * (size_t)B, B, sc.s[l]);
        }
        dense_kernel<<<blocks, 256, 0, stream>>>(positions, table, ws, B, sc);
        merge_kernel<<<blocks, 256, 0, stream>>>(ws, out, B);
    } else {
        hash_encode_kernel<<<blocks, 256, 0, stream>>>(positions, table, out, B, sc);
    }
}

// Round 6
// 873.943 us; speedup vs baseline: 1.0622x; 1.0622x over previous
//
#include <hip/hip_runtime.h>
#include <math.h>

// InstantNGP-style hash-grid encoder, 16 levels, FEAT=2, B=2M points.
//   dense levels 0..4 (res^3 <= 2^19), hashed levels 5..15 (size = 2^19 each)
//
// Measured model (r3-r5): divergent gathers are TCP-request bound, ~2 cyc per
// 8B lane-request; dwordx4 divergent loads split into 2 requests (r5: fine
// 51.6 -> 63us = exactly 10/8 chunks). Strategy:
//   - convert table once per launch to bf16x2 PAIRED entries: 8B = entries
//     {2j, 2j+1}. Fine hash: h(cx=1)=h(cx=0)^1 for even gx -> ONE 8B request
//     serves both x-corners; odd-gx lanes issue one extra 8B request.
//     Requests/pt/level: 8 -> 6 avg, all 8B.
//   - dense levels keep f32 x-paired loads (known 162us; separate experiment).
//   - ws staging as bf16x2; merge is pure streaming.
#define NLEVELS 16
#define BEGIN_FAST 5
#define P2 2654435761u
#define P3 805459861u
#define FAST_MASK 524287u  // size = 2^19 for all hashed levels
#define TOTAL_ENTRIES 6098120u

constexpr unsigned kRes[NLEVELS] = {16u, 23u, 31u, 43u, 59u, 81u, 112u, 154u, 213u, 295u, 407u, 562u, 777u, 1073u, 1483u, 2048u};
constexpr unsigned kSize[NLEVELS] = {
    4096u, 12168u, 29792u, 79512u, 205384u,
    524288u, 524288u, 524288u, 524288u, 524288u, 524288u,
    524288u, 524288u, 524288u, 524288u, 524288u};
constexpr unsigned kOffset[NLEVELS] = {
    0u,       4096u,    16264u,   46056u,   125568u,  330952u,
    855240u,  1379528u, 1903816u, 2428104u, 2952392u, 3476680u,
    4000968u, 4525256u, 5049544u, 5573832u};

struct Scales {
    float s[NLEVELS];
};

typedef float fvec2 __attribute__((ext_vector_type(2)));
typedef float fvec4 __attribute__((ext_vector_type(4)));
typedef float fvec4a8 __attribute__((ext_vector_type(4), aligned(8)));
typedef unsigned uvec2 __attribute__((ext_vector_type(2)));

// pack two f32 -> bf16x2 (round-to-nearest-even), lo = a, hi = b
__device__ __forceinline__ unsigned bfpack(float a, float b) {
    unsigned ua = __float_as_uint(a);
    unsigned ub = __float_as_uint(b);
    ua = (ua + 0x7FFFu + ((ua >> 16) & 1u)) >> 16;
    ub = (ub + 0x7FFFu + ((ub >> 16) & 1u)) & 0xFFFF0000u;
    return ua | ub;
}
__device__ __forceinline__ float bf_lo(unsigned e) { return __uint_as_float(e << 16); }
__device__ __forceinline__ float bf_hi(unsigned e) { return __uint_as_float(e & 0xFFFF0000u); }

// --------- convert: f32 table -> bf16x2 paired entries (8B per 2 entries) ----
__global__ __launch_bounds__(256) void convert_kernel(
    const fvec4* __restrict__ t4,   // table viewed as pairs of float2
    uvec2* __restrict__ bp,         // paired bf16 table
    int npairs)
{
    int j = blockIdx.x * 256 + threadIdx.x;
    if (j >= npairs) return;
    const fvec4 v = __builtin_nontemporal_load(t4 + j);
    uvec2 r = {bfpack(v.x, v.y), bfpack(v.z, v.w)};
    __builtin_nontemporal_store(r, bp + j);
}

// ---------------- fine (hashed) level: paired-bf16 slice, 2MB, L2-fit --------
__global__ __launch_bounds__(256) void fine_level_kernel(
    const float* __restrict__ positions,  // [B,3]
    const uvec2* __restrict__ bt,         // paired bf16 table + kOffset[l]/2
    unsigned* __restrict__ wsl,           // ws slice [B], bf16x2 packed
    int B, float s)
{
    int p = blockIdx.x * 256 + threadIdx.x;
    if (p >= B) return;

    const float x = __builtin_nontemporal_load(positions + 3 * p + 0);
    const float y = __builtin_nontemporal_load(positions + 3 * p + 1);
    const float z = __builtin_nontemporal_load(positions + 3 * p + 2);

    const float px = x * s + 0.5f;
    const float py = y * s + 0.5f;
    const float pz = z * s + 0.5f;
    const float flx = floorf(px), fly = floorf(py), flz = floorf(pz);
    const float rx = px - flx, ry = py - fly, rz = pz - flz;
    const unsigned gx = (unsigned)flx;
    const unsigned gy = (unsigned)fly;
    const unsigned gz = (unsigned)flz;
    const float wx0 = 1.0f - rx, wy0 = 1.0f - ry, wz0 = 1.0f - rz;

    const unsigned hy0 = gy * P2, hy1 = hy0 + P2;
    const unsigned hz0 = gz * P3, hz1 = hz0 + P3;
    const bool odd = (gx & 1u) != 0u;
    const unsigned gx1 = gx + 1u;

    float ax = 0.0f, ay = 0.0f;
#pragma unroll
    for (int cc = 0; cc < 4; ++cc) {              // (cy, cz)
        const unsigned cy = (unsigned)(cc & 1);
        const unsigned cz = (unsigned)(cc >> 1);
        const float wyz = (cy ? ry : wy0) * (cz ? rz : wz0);
        const unsigned A = (cy ? hy1 : hy0) ^ (cz ? hz1 : hz0);
        const unsigned h0 = (gx ^ A) & FAST_MASK;
        const uvec2 q0 = bt[h0 >> 1];
        const bool h0odd = (h0 & 1u) != 0u;
        const unsigned e0 = h0odd ? q0.y : q0.x;
        unsigned e1 = h0odd ? q0.x : q0.y;        // valid when gx even (h1=h0^1)
        if (odd) {                                // divergent: ~half the lanes
            const unsigned h1 = (gx1 ^ A) & FAST_MASK;
            const uvec2 q1 = bt[h1 >> 1];
            e1 = (h1 & 1u) ? q1.y : q1.x;
        }
        ax += wyz * (wx0 * bf_lo(e0) + rx * bf_lo(e1));
        ay += wyz * (wx0 * bf_hi(e0) + rx * bf_hi(e1));
    }
    __builtin_nontemporal_store(bfpack(ax, ay), wsl + p);
}

// ---------------- dense levels 0..4 -> ws slices 0..4 (f32 table) ------------
__global__ __launch_bounds__(256) void dense_kernel(
    const float* __restrict__ positions,  // [B,3]
    const float2* __restrict__ table,     // full f32 table
    unsigned* __restrict__ ws,            // slices [16][B]; writes 0..4
    int B, Scales sc)
{
    int p = blockIdx.x * 256 + threadIdx.x;
    if (p >= B) return;

    const float x = __builtin_nontemporal_load(positions + 3 * p + 0);
    const float y = __builtin_nontemporal_load(positions + 3 * p + 1);
    const float z = __builtin_nontemporal_load(positions + 3 * p + 2);

#pragma unroll
    for (int l = 0; l < BEGIN_FAST; ++l) {
        const float s = sc.s[l];
        const float px = x * s + 0.5f;
        const float py = y * s + 0.5f;
        const float pz = z * s + 0.5f;
        const float flx = floorf(px), fly = floorf(py), flz = floorf(pz);
        const float rx = px - flx, ry = py - fly, rz = pz - flz;
        const unsigned gx = (unsigned)flx;
        const unsigned gy = (unsigned)fly;
        const unsigned gz = (unsigned)flz;
        const float wx0 = 1.0f - rx, wy0 = 1.0f - ry, wz0 = 1.0f - rz;

        const float2* tab = table + kOffset[l];
        const unsigned res = kRes[l];

        float ax = 0.0f, ay = 0.0f;
#pragma unroll
        for (int cc = 0; cc < 4; ++cc) {          // (cy, cz); x-pair fused
            const unsigned cy = (unsigned)(cc & 1);
            const unsigned cz = (unsigned)(cc >> 1);
            const float wyz = (cy ? ry : wy0) * (cz ? rz : wz0);
            const unsigned h0 = gx + (gy + cy) * res + (gz + cz) * (res * res);
            const unsigned idx0 = h0 % kSize[l];
            const fvec4 tt = *reinterpret_cast<const fvec4a8*>(tab + idx0);
            float t1x = tt.z, t1y = tt.w;
            if (idx0 == kSize[l] - 1) {           // (h0+1) % size wrapped to 0
                const float2 tf = tab[0];
                t1x = tf.x; t1y = tf.y;
            }
            ax += wyz * (wx0 * tt.x + rx * t1x);
            ay += wyz * (wx0 * tt.y + rx * t1y);
        }
        __builtin_nontemporal_store(bfpack(ax, ay), ws + (size_t)l * (size_t)B + p);
    }
}

// ---------------- merge: pure streaming, no gathers --------------------------
__global__ __launch_bounds__(256) void merge_kernel(
    const unsigned* __restrict__ ws,  // [16][B] bf16x2 packed
    float* __restrict__ out,          // [B,32]
    int B)
{
    int p = blockIdx.x * 256 + threadIdx.x;
    if (p >= B) return;

    float o[2 * NLEVELS];
#pragma unroll
    for (int l = 0; l < NLEVELS; ++l) {
        const unsigned v = __builtin_nontemporal_load(ws + (size_t)l * (size_t)B + p);
        o[2 * l + 0] = bf_lo(v);
        o[2 * l + 1] = bf_hi(v);
    }
    float* op = out + (size_t)p * (2 * NLEVELS);
#pragma unroll
    for (int i = 0; i < 8; ++i) {
        fvec4 v = {o[4 * i + 0], o[4 * i + 1], o[4 * i + 2], o[4 * i + 3]};
        *(reinterpret_cast<fvec4*>(op) + i) = v;
    }
}

// ---------------- fallback: monolithic f32 (if ws too small) -----------------
__global__ __launch_bounds__(256) void hash_encode_kernel(
    const float* __restrict__ positions,
    const float2* __restrict__ table,
    float* __restrict__ out,
    int B, Scales sc)
{
    int p = blockIdx.x * 256 + threadIdx.x;
    if (p >= B) return;

    const float x = positions[3 * p + 0];
    const float y = positions[3 * p + 1];
    const float z = positions[3 * p + 2];

    float o[2 * NLEVELS];

#pragma unroll
    for (int l = 0; l < NLEVELS; ++l) {
        const float s = sc.s[l];
        const float px = x * s + 0.5f;
        const float py = y * s + 0.5f;
        const float pz = z * s + 0.5f;
        const float flx = floorf(px), fly = floorf(py), flz = floorf(pz);
        const float rx = px - flx, ry = py - fly, rz = pz - flz;
        const unsigned gx = (unsigned)flx;
        const unsigned gy = (unsigned)fly;
        const unsigned gz = (unsigned)flz;
        const float wx0 = 1.0f - rx, wy0 = 1.0f - ry, wz0 = 1.0f - rz;

        float ax = 0.0f, ay = 0.0f;
#pragma unroll
        for (int c = 0; c < 8; ++c) {
            const unsigned cx = (unsigned)(c & 1);
            const unsigned cy = (unsigned)((c >> 1) & 1);
            const unsigned cz = (unsigned)((c >> 2) & 1);
            const unsigned pgx = gx + cx;
            const unsigned pgy = gy + cy;
            const unsigned pgz = gz + cz;
            const float w = (cx ? rx : wx0) * (cy ? ry : wy0) * (cz ? rz : wz0);
            unsigned h;
            if (l < BEGIN_FAST) {
                h = pgx + pgy * kRes[l] + pgz * (kRes[l] * kRes[l]);
            } else {
                h = pgx ^ (pgy * P2) ^ (pgz * P3);
            }
            const unsigned idx = (h % kSize[l]) + kOffset[l];
            const float2 t = table[idx];
            ax += w * t.x;
            ay += w * t.y;
        }
        o[2 * l + 0] = ax;
        o[2 * l + 1] = ay;
    }

    float* op = out + (size_t)p * (2 * NLEVELS);
#pragma unroll
    for (int i = 0; i < 8; ++i) {
        fvec4 v = {o[4 * i + 0], o[4 * i + 1], o[4 * i + 2], o[4 * i + 3]};
        *(reinterpret_cast<fvec4*>(op) + i) = v;
    }
}

extern "C" void kernel_launch(void* const* d_in, const int* in_sizes, int n_in,
                              void* d_out, int out_size, void* d_ws, size_t ws_size,
                              hipStream_t stream) {
    const float* positions = (const float*)d_in[0];
    const float2* table = (const float2*)d_in[1];
    float* out = (float*)d_out;

    const int B = in_sizes[0] / 3;

    Scales sc;
    const double log_b = log(2048.0 / 16.0) / (NLEVELS - 1);
    for (int l = 0; l < NLEVELS; ++l) {
        sc.s[l] = (float)(16.0 * exp((double)l * log_b) - 1.0);
    }

    const int blocks = (B + 255) / 256;
    const int npairs = (int)(TOTAL_ENTRIES / 2u);           // 3,049,060
    const size_t slices_bytes = (size_t)NLEVELS * (size_t)B * sizeof(unsigned);
    const size_t bt_bytes = (size_t)npairs * sizeof(uvec2); // 24.4 MB
    const size_t ws_need = slices_bytes + bt_bytes;

    if (ws_size >= ws_need) {
        unsigned* ws = (unsigned*)d_ws;                      // 16 slices [B]
        uvec2* bt = (uvec2*)((char*)d_ws + slices_bytes);    // paired bf16 table

        convert_kernel<<<(npairs + 255) / 256, 256, 0, stream>>>(
            (const fvec4*)table, bt, npairs);

        for (int l = BEGIN_FAST; l < NLEVELS; ++l) {
            fine_level_kernel<<<blocks, 256, 0, stream>>>(
                positions, bt + kOffset[l] / 2,
                ws + (size_t)l * (size_t)B, B, sc.s[l]);
        }
        dense_kernel<<<blocks, 256, 0, stream>>>(positions, table, ws, B, sc);
        merge_kernel<<<blocks, 256, 0, stream>>>(ws, out, B);
    } else {
        hash_encode_kernel<<<blocks, 256, 0, stream>>>(positions, table, out, B, sc);
    }
}